// Round 5
// baseline (97.469 us; speedup 1.0000x reference)
//
#include <hip/hip_runtime.h>

#define CIN    4096
#define OUTR   16384
#define NPOS   4096
#define CIN_G  64

typedef __attribute__((ext_vector_type(8))) short  bf16x8;
typedef __attribute__((ext_vector_type(4))) float  f32x4;
typedef __attribute__((ext_vector_type(4))) _Float16 h4v;
typedef __attribute__((ext_vector_type(2))) _Float16 h2v;

__device__ inline short bf16rne(float f) {
    unsigned u = __float_as_uint(f);
    return (short)((u + 0x7FFFu + ((u >> 16) & 1u)) >> 16);
}

__device__ inline bf16x8 pack8(float4 a, float4 b) {
    bf16x8 v;
    v[0] = bf16rne(a.x); v[1] = bf16rne(a.y); v[2] = bf16rne(a.z); v[3] = bf16rne(a.w);
    v[4] = bf16rne(b.x); v[5] = bf16rne(b.y); v[6] = bf16rne(b.z); v[7] = bf16rne(b.w);
    return v;
}

// ---------------- Phase 1: pipelined grouped GEMM ----------------
// Grid = 1024 blocks = 64 groups x 16 stripes (256 pos = 4 tiles of 64).
// XCD-chunked swizzle: each XCD gets 128 consecutive work-units = 8 whole groups
// (W slices L2-local). 48KB LDS -> 3 blocks/CU resident.
__global__ __launch_bounds__(256, 3) void fc2_phase1(
    const float* __restrict__ In,    // [NPOS][CIN]
    const float* __restrict__ W,     // [OUTR][CIN_G]
    const float* __restrict__ Bias,  // [OUTR]
    _Float16* __restrict__ Y)        // [NPOS][OUTR]
{
    __shared__ __align__(16) char lds[49152];
    char* lds_w   = lds;            // [256 ch][128B] bf16 swizzled (prologue only)
    char* lds_o   = lds;            // [64 pos][512B] f16 swizzled (loop; aliases lds_w)
    char* lds_in0 = lds + 32768;    // [64 pos][128B] bf16 swizzled
    char* lds_in1 = lds + 40960;

    const int t   = threadIdx.x;
    // bijective XCD chunk: hw XCD = bid&7 -> work-units (bid&7)*128 + bid>>3
    const int swz = ((blockIdx.x & 7) << 7) + (blockIdx.x >> 3);
    const int g      = swz >> 4;      // 8 consecutive groups per XCD chunk
    const int stripe = swz & 15;
    const int pbase  = stripe * 256;  // 4 tiles of 64 positions
    const int w  = t >> 6, l = t & 63;
    const int lr = l & 15, lh = l >> 4;

    // ---- prologue: stage W (256x64), In tile 0, bias regs ----
#pragma unroll
    for (int it = 0; it < 8; it++) {
        int q = it * 256 + t;
        int row = q >> 3, c8 = q & 7;
        const float* src = W + (size_t)(g * 256 + row) * CIN_G + c8 * 8;
        float4 a = *(const float4*)src;
        float4 b = *(const float4*)(src + 4);
        *(bf16x8*)(lds_w + row * 128 + ((c8 * 16) ^ ((row & 7) << 4))) = pack8(a, b);
    }
#pragma unroll
    for (int it = 0; it < 2; it++) {
        int q = it * 256 + t;
        int row = q >> 3, c8 = q & 7;
        const float* src = In + (size_t)(pbase + row) * CIN + g * CIN_G + c8 * 8;
        float4 a = *(const float4*)src;
        float4 b = *(const float4*)(src + 4);
        *(bf16x8*)(lds_in0 + row * 128 + ((c8 * 16) ^ ((row & 7) << 4))) = pack8(a, b);
    }
    float bv[4][4];
#pragma unroll
    for (int m = 0; m < 4; m++) {
        float4 bb = *(const float4*)(Bias + g * 256 + w * 64 + m * 16 + lh * 4);
        bv[m][0] = bb.x; bv[m][1] = bb.y; bv[m][2] = bb.z; bv[m][3] = bb.w;
    }
    __syncthreads();

    // ---- hoist W fragments into registers (lds_w dead afterwards) ----
    bf16x8 afr[2][4];
#pragma unroll
    for (int kk = 0; kk < 2; kk++) {
        const int ksl = (kk * 4 + lh) * 16;
#pragma unroll
        for (int m = 0; m < 4; m++) {
            int row = w * 64 + m * 16 + lr;
            afr[kk][m] = *(const bf16x8*)(lds_w + row * 128 + (ksl ^ ((row & 7) << 4)));
        }
    }

    // ---- main loop over 4 position tiles ----
    for (int i = 0; i < 4; i++) {
        char* bufc = (i & 1) ? lds_in1 : lds_in0;
        char* bufn = (i & 1) ? lds_in0 : lds_in1;
        const int p0 = pbase + i * 64;

        // (a) coop-store previous tile's Y (stores fly across the compute body)
        if (i > 0) {
#pragma unroll
            for (int it = 0; it < 8; it++) {
                int q = it * 256 + t;
                int pos = q >> 5, c16 = q & 31;
                uint4 v = *(const uint4*)(lds_o + pos * 512 + ((c16 * 16) ^ ((pos & 7) << 4)));
                *(uint4*)(Y + (size_t)(p0 - 64 + pos) * OUTR + g * 256 + c16 * 8) = v;
            }
        }

        // (b) issue next In tile's global loads early
        float4 na0, na1, nb0, nb1;
        int nrow0 = 0, nc80 = 0, nrow1 = 0, nc81 = 0;
        if (i < 3) {
            int q0 = t;
            nrow0 = q0 >> 3; nc80 = q0 & 7;
            const float* s0 = In + (size_t)(p0 + 64 + nrow0) * CIN + g * CIN_G + nc80 * 8;
            na0 = *(const float4*)s0; na1 = *(const float4*)(s0 + 4);
            int q1 = 256 + t;
            nrow1 = q1 >> 3; nc81 = q1 & 7;
            const float* s1 = In + (size_t)(p0 + 64 + nrow1) * CIN + g * CIN_G + nc81 * 8;
            nb0 = *(const float4*)s1; nb1 = *(const float4*)(s1 + 4);
        }

        // (c) fragments + MFMA
        f32x4 acc[4][4];
#pragma unroll
        for (int m = 0; m < 4; m++)
#pragma unroll
            for (int n = 0; n < 4; n++)
                acc[m][n] = (f32x4){0.f, 0.f, 0.f, 0.f};
#pragma unroll
        for (int kk = 0; kk < 2; kk++) {
            const int ksl = (kk * 4 + lh) * 16;
            bf16x8 bfr[4];
#pragma unroll
            for (int n = 0; n < 4; n++) {
                int row = n * 16 + lr;
                bfr[n] = *(const bf16x8*)(bufc + row * 128 + (ksl ^ ((row & 7) << 4)));
            }
#pragma unroll
            for (int m = 0; m < 4; m++)
#pragma unroll
                for (int n = 0; n < 4; n++)
                    acc[m][n] = __builtin_amdgcn_mfma_f32_16x16x32_bf16(afr[kk][m], bfr[n], acc[m][n], 0, 0, 0);
        }

        // (d) pack + LDS-write next In tile
        if (i < 3) {
            *(bf16x8*)(bufn + nrow0 * 128 + ((nc80 * 16) ^ ((nrow0 & 7) << 4))) = pack8(na0, na1);
            *(bf16x8*)(bufn + nrow1 * 128 + ((nc81 * 16) ^ ((nrow1 & 7) << 4))) = pack8(nb0, nb1);
        }

        __syncthreads();   // buf[i] reads done; next-tile writes done; lds_o free

        // (f) epilogue: bias + cvt f16 -> lds_o
#pragma unroll
        for (int m = 0; m < 4; m++) {
            const int c_loc = w * 64 + m * 16 + lh * 4;
#pragma unroll
            for (int n = 0; n < 4; n++) {
                const int p = n * 16 + lr;
                h4v hv;
#pragma unroll
                for (int q = 0; q < 4; q++)
                    hv[q] = (_Float16)(acc[m][n][q] + bv[m][q]);
                *(h4v*)(lds_o + p * 512 + ((c_loc * 2) ^ ((p & 7) << 4))) = hv;
            }
        }
        __syncthreads();   // lds_o visible to all
    }

    // ---- tail: store last tile ----
    {
        const int p0 = pbase + 3 * 64;
#pragma unroll
        for (int it = 0; it < 8; it++) {
            int q = it * 256 + t;
            int pos = q >> 5, c16 = q & 31;
            uint4 v = *(const uint4*)(lds_o + pos * 512 + ((c16 * 16) ^ ((pos & 7) << 4)));
            *(uint4*)(Y + (size_t)(p0 + pos) * OUTR + g * 256 + c16 * 8) = v;
        }
    }
}

// ---------------- Phase 2: softmax-attention mix (unchanged from R4) ----------------
__device__ inline void unpack2(unsigned u, float& a, float& b) {
    h2v h = __builtin_bit_cast(h2v, u);
    a = (float)h[0]; b = (float)h[1];
}

__device__ inline float wredsum(float v) {
#pragma unroll
    for (int off = 32; off; off >>= 1) v += __shfl_xor(v, off);
    return v;
}

__device__ inline int sswz(int a) { return a ^ (((a >> 7) & 7) << 4); }

__global__ __launch_bounds__(256) void fc2_phase2(
    const _Float16* __restrict__ Y,  // [NPOS][OUTR]
    float* __restrict__ Out)         // [NPOS][COUT]
{
    const int p = blockIdx.x;
    const int t = threadIdx.x;
    const int w = t >> 6, l = t & 63;
    const _Float16* yrow = Y + (size_t)p * OUTR;

    __shared__ __align__(16) char s_x[16384];
    __shared__ float redbuf[4][8];

    float x[4][16];
#pragma unroll
    for (int r = 0; r < 4; r++) {
        const uint4* ptr = (const uint4*)(yrow + r * 4096 + t * 16);
        uint4 u0 = ptr[0], u1 = ptr[1];
        unpack2(u0.x, x[r][0],  x[r][1]);
        unpack2(u0.y, x[r][2],  x[r][3]);
        unpack2(u0.z, x[r][4],  x[r][5]);
        unpack2(u0.w, x[r][6],  x[r][7]);
        unpack2(u1.x, x[r][8],  x[r][9]);
        unpack2(u1.y, x[r][10], x[r][11]);
        unpack2(u1.z, x[r][12], x[r][13]);
        unpack2(u1.w, x[r][14], x[r][15]);
    }

#pragma unroll
    for (int r = 0; r < 4; r++) {
        float4 v = make_float4(x[r][0], x[r][4], x[r][8], x[r][12]);
        *(float4*)(s_x + sswz(r * 4096 + t * 16)) = v;
    }

    float dr[4] = {0, 0, 0, 0}, ar[4] = {0, 0, 0, 0};
#pragma unroll
    for (int j = 0; j < 16; j++) {
        float xs = x[0][j] + x[1][j] + x[2][j] + x[3][j];
#pragma unroll
        for (int r = 0; r < 4; r++) {
            float e = __expf(x[r][j]);
            dr[r] += e;
            ar[r] += e * xs;
        }
    }
#pragma unroll
    for (int r = 0; r < 4; r++) { dr[r] = wredsum(dr[r]); ar[r] = wredsum(ar[r]); }
    if (l == 0) {
#pragma unroll
        for (int r = 0; r < 4; r++) { redbuf[w][r] = dr[r]; redbuf[w][4 + r] = ar[r]; }
    }
    __syncthreads();

    float kr[4];
#pragma unroll
    for (int r = 0; r < 4; r++) {
        float d = redbuf[0][r] + redbuf[1][r] + redbuf[2][r] + redbuf[3][r];
        float a = redbuf[0][4 + r] + redbuf[1][4 + r] + redbuf[2][4 + r] + redbuf[3][4 + r];
        kr[r] = a / d;
    }

    float sv[16];
#pragma unroll
    for (int c = 0; c < 4; c++) {
        float4 v = *(const float4*)(s_x + sswz(t * 64 + c * 16));
        sv[4 * c] = v.x; sv[4 * c + 1] = v.y; sv[4 * c + 2] = v.z; sv[4 * c + 3] = v.w;
    }

    float outv[16];
#pragma unroll
    for (int j = 0; j < 16; j++)
        outv[j] = sv[j] + x[0][j] * kr[0] + x[1][j] * kr[1] + x[2][j] * kr[2] + x[3][j] * kr[3];

    float4* op = (float4*)(Out + (size_t)p * 4096 + t * 16);
#pragma unroll
    for (int j = 0; j < 4; j++)
        op[j] = make_float4(outv[4 * j], outv[4 * j + 1], outv[4 * j + 2], outv[4 * j + 3]);
}

extern "C" void kernel_launch(void* const* d_in, const int* in_sizes, int n_in,
                              void* d_out, int out_size, void* d_ws, size_t ws_size,
                              hipStream_t stream) {
    const float* In   = (const float*)d_in[0];
    const float* W    = (const float*)d_in[1];
    const float* Bias = (const float*)d_in[2];
    float* Out = (float*)d_out;
    _Float16* Y = (_Float16*)d_ws;   // NPOS*OUTR*2 = 128 MiB

    fc2_phase1<<<dim3(1024), dim3(256), 0, stream>>>(In, W, Bias, Y);
    fc2_phase2<<<dim3(4096), dim3(256), 0, stream>>>(Y, Out);
}

// Round 6
// 75.626 us; speedup vs baseline: 1.2888x; 1.2888x over previous
//
#include <hip/hip_runtime.h>

#define CIN    4096
#define OUTR   16384
#define NPOS   4096
#define CIN_G  64

typedef __attribute__((ext_vector_type(8))) short  bf16x8;
typedef __attribute__((ext_vector_type(4))) float  f32x4;
typedef __attribute__((ext_vector_type(4))) _Float16 h4v;
typedef __attribute__((ext_vector_type(2))) _Float16 h2v;

__device__ inline short bf16rne(float f) {
    unsigned u = __float_as_uint(f);
    return (short)((u + 0x7FFFu + ((u >> 16) & 1u)) >> 16);
}

__device__ inline bf16x8 pack8(float4 a, float4 b) {
    bf16x8 v;
    v[0] = bf16rne(a.x); v[1] = bf16rne(a.y); v[2] = bf16rne(a.z); v[3] = bf16rne(a.w);
    v[4] = bf16rne(b.x); v[5] = bf16rne(b.y); v[6] = bf16rne(b.z); v[7] = bf16rne(b.w);
    return v;
}

// ---------------- Phase 1: pipelined grouped GEMM (R3 geometry + XCD swizzle) ----------------
// Grid = 512 blocks = 64 groups x 8 stripes of 512 positions (8 tiles of 64).
// XCD chunk: hw XCD = bid&7 -> each XCD owns 8 whole groups (W L2-local, ~512KB/XCD).
__global__ __launch_bounds__(256, 2) void fc2_phase1(
    const float* __restrict__ In,    // [NPOS][CIN]
    const float* __restrict__ W,     // [OUTR][CIN_G]
    const float* __restrict__ Bias,  // [OUTR]
    _Float16* __restrict__ Y)        // [NPOS][OUTR]
{
    __shared__ __align__(16) char lds[49152];
    char* lds_w   = lds;            // [256 ch][128B] bf16 swizzled (prologue only)
    char* lds_o   = lds;            // [64 pos][512B] f16 swizzled (loop; aliases lds_w)
    char* lds_in0 = lds + 32768;    // [64 pos][128B] bf16 swizzled
    char* lds_in1 = lds + 40960;

    const int t   = threadIdx.x;
    // bijective XCD chunk for 512 blocks: swz = (bid&7)*64 + bid>>3
    const int swz    = ((blockIdx.x & 7) << 6) + (blockIdx.x >> 3);
    const int g      = swz >> 3;      // 8 consecutive groups per XCD
    const int stripe = swz & 7;
    const int pbase  = stripe * 512;
    const int w  = t >> 6, l = t & 63;
    const int lr = l & 15, lh = l >> 4;

    // ---- prologue: stage W (256x64), In tile 0, bias regs ----
#pragma unroll
    for (int it = 0; it < 8; it++) {
        int q = it * 256 + t;
        int row = q >> 3, c8 = q & 7;
        const float* src = W + (size_t)(g * 256 + row) * CIN_G + c8 * 8;
        float4 a = *(const float4*)src;
        float4 b = *(const float4*)(src + 4);
        *(bf16x8*)(lds_w + row * 128 + ((c8 * 16) ^ ((row & 7) << 4))) = pack8(a, b);
    }
#pragma unroll
    for (int it = 0; it < 2; it++) {
        int q = it * 256 + t;
        int row = q >> 3, c8 = q & 7;
        const float* src = In + (size_t)(pbase + row) * CIN + g * CIN_G + c8 * 8;
        float4 a = *(const float4*)src;
        float4 b = *(const float4*)(src + 4);
        *(bf16x8*)(lds_in0 + row * 128 + ((c8 * 16) ^ ((row & 7) << 4))) = pack8(a, b);
    }
    float bv[4][4];
#pragma unroll
    for (int m = 0; m < 4; m++) {
        float4 bb = *(const float4*)(Bias + g * 256 + w * 64 + m * 16 + lh * 4);
        bv[m][0] = bb.x; bv[m][1] = bb.y; bv[m][2] = bb.z; bv[m][3] = bb.w;
    }
    __syncthreads();

    // ---- hoist W fragments into registers (lds_w dead afterwards) ----
    bf16x8 afr[2][4];
#pragma unroll
    for (int kk = 0; kk < 2; kk++) {
        const int ksl = (kk * 4 + lh) * 16;
#pragma unroll
        for (int m = 0; m < 4; m++) {
            int row = w * 64 + m * 16 + lr;
            afr[kk][m] = *(const bf16x8*)(lds_w + row * 128 + (ksl ^ ((row & 7) << 4)));
        }
    }

    // ---- main loop over 8 position tiles ----
    for (int i = 0; i < 8; i++) {
        char* bufc = (i & 1) ? lds_in1 : lds_in0;
        char* bufn = (i & 1) ? lds_in0 : lds_in1;
        const int p0 = pbase + i * 64;

        // (a) issue next In tile's global loads first (max latency cover)
        float4 na0, na1, nb0, nb1;
        int nrow0 = 0, nc80 = 0, nrow1 = 0, nc81 = 0;
        if (i < 7) {
            int q0 = t;
            nrow0 = q0 >> 3; nc80 = q0 & 7;
            const float* s0 = In + (size_t)(p0 + 64 + nrow0) * CIN + g * CIN_G + nc80 * 8;
            na0 = *(const float4*)s0; na1 = *(const float4*)(s0 + 4);
            int q1 = 256 + t;
            nrow1 = q1 >> 3; nc81 = q1 & 7;
            const float* s1 = In + (size_t)(p0 + 64 + nrow1) * CIN + g * CIN_G + nc81 * 8;
            nb0 = *(const float4*)s1; nb1 = *(const float4*)(s1 + 4);
        }

        // (b) coop-store previous tile's Y (stores fly across the compute body)
        if (i > 0) {
#pragma unroll
            for (int it = 0; it < 8; it++) {
                int q = it * 256 + t;
                int pos = q >> 5, c16 = q & 31;
                uint4 v = *(const uint4*)(lds_o + pos * 512 + ((c16 * 16) ^ ((pos & 7) << 4)));
                *(uint4*)(Y + (size_t)(p0 - 64 + pos) * OUTR + g * 256 + c16 * 8) = v;
            }
        }

        // (c) fragments + MFMA
        f32x4 acc[4][4];
#pragma unroll
        for (int m = 0; m < 4; m++)
#pragma unroll
            for (int n = 0; n < 4; n++)
                acc[m][n] = (f32x4){0.f, 0.f, 0.f, 0.f};
#pragma unroll
        for (int kk = 0; kk < 2; kk++) {
            const int ksl = (kk * 4 + lh) * 16;
            bf16x8 bfr[4];
#pragma unroll
            for (int n = 0; n < 4; n++) {
                int row = n * 16 + lr;
                bfr[n] = *(const bf16x8*)(bufc + row * 128 + (ksl ^ ((row & 7) << 4)));
            }
#pragma unroll
            for (int m = 0; m < 4; m++)
#pragma unroll
                for (int n = 0; n < 4; n++)
                    acc[m][n] = __builtin_amdgcn_mfma_f32_16x16x32_bf16(afr[kk][m], bfr[n], acc[m][n], 0, 0, 0);
        }

        // (d) pack + LDS-write next In tile
        if (i < 7) {
            *(bf16x8*)(bufn + nrow0 * 128 + ((nc80 * 16) ^ ((nrow0 & 7) << 4))) = pack8(na0, na1);
            *(bf16x8*)(bufn + nrow1 * 128 + ((nc81 * 16) ^ ((nrow1 & 7) << 4))) = pack8(nb0, nb1);
        }

        __syncthreads();   // buf[i] reads done; next-tile writes done; lds_o free

        // (e) epilogue: bias + cvt f16 -> lds_o
#pragma unroll
        for (int m = 0; m < 4; m++) {
            const int c_loc = w * 64 + m * 16 + lh * 4;
#pragma unroll
            for (int n = 0; n < 4; n++) {
                const int p = n * 16 + lr;
                h4v hv;
#pragma unroll
                for (int q = 0; q < 4; q++)
                    hv[q] = (_Float16)(acc[m][n][q] + bv[m][q]);
                *(h4v*)(lds_o + p * 512 + ((c_loc * 2) ^ ((p & 7) << 4))) = hv;
            }
        }
        __syncthreads();   // lds_o visible to all
    }

    // ---- tail: store last tile ----
    {
        const int p0 = pbase + 7 * 64;
#pragma unroll
        for (int it = 0; it < 8; it++) {
            int q = it * 256 + t;
            int pos = q >> 5, c16 = q & 31;
            uint4 v = *(const uint4*)(lds_o + pos * 512 + ((c16 * 16) ^ ((pos & 7) << 4)));
            *(uint4*)(Y + (size_t)(p0 + pos) * OUTR + g * 256 + c16 * 8) = v;
        }
    }
}

// ---------------- Phase 2: softmax-attention mix (unchanged) ----------------
__device__ inline void unpack2(unsigned u, float& a, float& b) {
    h2v h = __builtin_bit_cast(h2v, u);
    a = (float)h[0]; b = (float)h[1];
}

__device__ inline float wredsum(float v) {
#pragma unroll
    for (int off = 32; off; off >>= 1) v += __shfl_xor(v, off);
    return v;
}

__device__ inline int sswz(int a) { return a ^ (((a >> 7) & 7) << 4); }

__global__ __launch_bounds__(256) void fc2_phase2(
    const _Float16* __restrict__ Y,  // [NPOS][OUTR]
    float* __restrict__ Out)         // [NPOS][COUT]
{
    const int p = blockIdx.x;
    const int t = threadIdx.x;
    const int w = t >> 6, l = t & 63;
    const _Float16* yrow = Y + (size_t)p * OUTR;

    __shared__ __align__(16) char s_x[16384];
    __shared__ float redbuf[4][8];

    float x[4][16];
#pragma unroll
    for (int r = 0; r < 4; r++) {
        const uint4* ptr = (const uint4*)(yrow + r * 4096 + t * 16);
        uint4 u0 = ptr[0], u1 = ptr[1];
        unpack2(u0.x, x[r][0],  x[r][1]);
        unpack2(u0.y, x[r][2],  x[r][3]);
        unpack2(u0.z, x[r][4],  x[r][5]);
        unpack2(u0.w, x[r][6],  x[r][7]);
        unpack2(u1.x, x[r][8],  x[r][9]);
        unpack2(u1.y, x[r][10], x[r][11]);
        unpack2(u1.z, x[r][12], x[r][13]);
        unpack2(u1.w, x[r][14], x[r][15]);
    }

#pragma unroll
    for (int r = 0; r < 4; r++) {
        float4 v = make_float4(x[r][0], x[r][4], x[r][8], x[r][12]);
        *(float4*)(s_x + sswz(r * 4096 + t * 16)) = v;
    }

    float dr[4] = {0, 0, 0, 0}, ar[4] = {0, 0, 0, 0};
#pragma unroll
    for (int j = 0; j < 16; j++) {
        float xs = x[0][j] + x[1][j] + x[2][j] + x[3][j];
#pragma unroll
        for (int r = 0; r < 4; r++) {
            float e = __expf(x[r][j]);
            dr[r] += e;
            ar[r] += e * xs;
        }
    }
#pragma unroll
    for (int r = 0; r < 4; r++) { dr[r] = wredsum(dr[r]); ar[r] = wredsum(ar[r]); }
    if (l == 0) {
#pragma unroll
        for (int r = 0; r < 4; r++) { redbuf[w][r] = dr[r]; redbuf[w][4 + r] = ar[r]; }
    }
    __syncthreads();

    float kr[4];
#pragma unroll
    for (int r = 0; r < 4; r++) {
        float d = redbuf[0][r] + redbuf[1][r] + redbuf[2][r] + redbuf[3][r];
        float a = redbuf[0][4 + r] + redbuf[1][4 + r] + redbuf[2][4 + r] + redbuf[3][4 + r];
        kr[r] = a / d;
    }

    float sv[16];
#pragma unroll
    for (int c = 0; c < 4; c++) {
        float4 v = *(const float4*)(s_x + sswz(t * 64 + c * 16));
        sv[4 * c] = v.x; sv[4 * c + 1] = v.y; sv[4 * c + 2] = v.z; sv[4 * c + 3] = v.w;
    }

    float outv[16];
#pragma unroll
    for (int j = 0; j < 16; j++)
        outv[j] = sv[j] + x[0][j] * kr[0] + x[1][j] * kr[1] + x[2][j] * kr[2] + x[3][j] * kr[3];

    float4* op = (float4*)(Out + (size_t)p * 4096 + t * 16);
#pragma unroll
    for (int j = 0; j < 4; j++)
        op[j] = make_float4(outv[4 * j], outv[4 * j + 1], outv[4 * j + 2], outv[4 * j + 3]);
}

extern "C" void kernel_launch(void* const* d_in, const int* in_sizes, int n_in,
                              void* d_out, int out_size, void* d_ws, size_t ws_size,
                              hipStream_t stream) {
    const float* In   = (const float*)d_in[0];
    const float* W    = (const float*)d_in[1];
    const float* Bias = (const float*)d_in[2];
    float* Out = (float*)d_out;
    _Float16* Y = (_Float16*)d_ws;   // NPOS*OUTR*2 = 128 MiB

    fc2_phase1<<<dim3(512), dim3(256), 0, stream>>>(In, W, Bias, Y);
    fc2_phase2<<<dim3(4096), dim3(256), 0, stream>>>(Y, Out);
}